// Round 2
// baseline (348.946 us; speedup 1.0000x reference)
//
#include <hip/hip_runtime.h>
#include <hip/hip_bf16.h>

typedef unsigned short u16;
typedef __bf16 bf16x8 __attribute__((ext_vector_type(8)));
typedef float f32x4 __attribute__((ext_vector_type(4)));

#define NTOK 32768   // B*S = 8*4096
#define DIM  512
#define KC   4096

__device__ __forceinline__ u16 f2b(float f) {
  __hip_bfloat16 h = __float2bfloat16(f);
  return *reinterpret_cast<u16*>(&h);
}

__device__ __forceinline__ void gload_lds16(const void* g, void* l) {
  __builtin_amdgcn_global_load_lds(
      (__attribute__((address_space(1))) void*)g,
      (__attribute__((address_space(3))) void*)l,
      16, 0, 0);
}

// ---------------- prep: fp32 -> bf16 conversion (8 elems/thread) -------------
__global__ void cvt8(const float* __restrict__ in, u16* __restrict__ out, int n8) {
  int i = blockIdx.x * blockDim.x + threadIdx.x;
  if (i >= n8) return;
  const float4* p = reinterpret_cast<const float4*>(in) + 2 * (size_t)i;
  float4 a = p[0], b = p[1];
  uint4 v;
  v.x = (unsigned)f2b(a.x) | ((unsigned)f2b(a.y) << 16);
  v.y = (unsigned)f2b(a.z) | ((unsigned)f2b(a.w) << 16);
  v.z = (unsigned)f2b(b.x) | ((unsigned)f2b(b.y) << 16);
  v.w = (unsigned)f2b(b.z) | ((unsigned)f2b(b.w) << 16);
  reinterpret_cast<uint4*>(out)[i] = v;
}

// codebook -> bf16, plus per-row squared L2 norm (fp32, exact)
__global__ void cvt_codebook(const float* __restrict__ cb, u16* __restrict__ cbb,
                             float* __restrict__ cnorm) {
  int k = blockIdx.x;          // 0..4095
  int t = threadIdx.x;         // 0..255
  float c0 = cb[(size_t)k * DIM + t];
  float c1 = cb[(size_t)k * DIM + 256 + t];
  cbb[(size_t)k * DIM + t]       = f2b(c0);
  cbb[(size_t)k * DIM + 256 + t] = f2b(c1);
  float s = c0 * c0 + c1 * c1;
#pragma unroll
  for (int m = 1; m < 64; m <<= 1) s += __shfl_xor(s, m, 64);
  __shared__ float w4[4];
  if ((t & 63) == 0) w4[t >> 6] = s;
  __syncthreads();
  if (t == 0) cnorm[k] = w4[0] + w4[1] + w4[2] + w4[3];
}

// ---------------- argmin GEMM: scores = cnorm[k] - 2 * x.c ------------------
// 128x128 tile, BK=64 double-buffered, prefetch-before-compute (T3 minimum),
// 4 waves (2x2), mfma 16x16x32 bf16, global_load_lds w=16.
__global__ __launch_bounds__(256)
void argmin_gemm(const u16* __restrict__ Xb, const u16* __restrict__ Cb,
                 const float* __restrict__ cnorm,
                 float* __restrict__ pval, int* __restrict__ pidx) {
  __shared__ u16 As[2][128 * 64];
  __shared__ u16 Bs[2][128 * 64];
  __shared__ float rv[2][128];
  __shared__ int   ri[2][128];

  const int tid  = threadIdx.x;
  const int lane = tid & 63;
  const int wid  = tid >> 6;          // 0..3
  const int wr   = wid >> 1, wc = wid & 1;
  const int bm   = blockIdx.x;        // 0..255 token tiles
  const int bn   = blockIdx.y;        // 0..31  code tiles
  const int l15  = lane & 15, l4 = lane >> 4;
  const int srow = lane >> 3;         // 0..7 (staging)
  const int scol = (lane & 7) * 8;    // 0..56 (staging, elems)

  const u16* Xrow = Xb + (size_t)(bm * 128) * DIM;
  const u16* Crow = Cb + (size_t)(bn * 128) * DIM;

  auto stage = [&](int buf, int kk) {
#pragma unroll
    for (int i = 0; i < 4; i++) {
      int rA = (wid * 4 + i) * 8 + srow;   // 0..127
      gload_lds16(Xrow + (size_t)rA * DIM + kk + scol,
                  (void*)(As[buf] + (wid * 4 + i) * 512));
      gload_lds16(Crow + (size_t)rA * DIM + kk + scol,
                  (void*)(Bs[buf] + (wid * 4 + i) * 512));
    }
  };

  f32x4 acc[4][4];
#pragma unroll
  for (int i = 0; i < 4; i++)
#pragma unroll
    for (int j = 0; j < 4; j++)
#pragma unroll
      for (int r = 0; r < 4; r++) acc[i][j][r] = 0.f;

  stage(0, 0);
  __syncthreads();              // vmcnt(0) drain + barrier: buf0 ready
  int cur = 0;
  for (int t = 0; t < 8; ++t) {
    if (t < 7) stage(cur ^ 1, (t + 1) * 64);   // prefetch next tile (latency hidden)
#pragma unroll
    for (int ks = 0; ks < 2; ks++) {
      bf16x8 af[4], bfr[4];
#pragma unroll
      for (int mi = 0; mi < 4; mi++) {
        int row = wr * 64 + mi * 16 + l15;
        af[mi] = *reinterpret_cast<const bf16x8*>(As[cur] + row * 64 + ks * 32 + l4 * 8);
      }
#pragma unroll
      for (int ni = 0; ni < 4; ni++) {
        int row = wc * 64 + ni * 16 + l15;
        bfr[ni] = *reinterpret_cast<const bf16x8*>(Bs[cur] + row * 64 + ks * 32 + l4 * 8);
      }
#pragma unroll
      for (int mi = 0; mi < 4; mi++)
#pragma unroll
        for (int ni = 0; ni < 4; ni++)
          acc[mi][ni] = __builtin_amdgcn_mfma_f32_16x16x32_bf16(
              af[mi], bfr[ni], acc[mi][ni], 0, 0, 0);
    }
    __syncthreads();            // drains prefetch (vmcnt 0) + lgkm; next buf ready
    cur ^= 1;
  }

  // epilogue: per-token argmin over this block's 128 codes
  float cn[4];
#pragma unroll
  for (int ni = 0; ni < 4; ni++)
    cn[ni] = cnorm[bn * 128 + wc * 64 + ni * 16 + l15];

#pragma unroll
  for (int mi = 0; mi < 4; mi++) {
#pragma unroll
    for (int r = 0; r < 4; r++) {
      float best = 1e30f;
      int bi = 0;
#pragma unroll
      for (int ni = 0; ni < 4; ni++) {
        float v = cn[ni] - 2.0f * acc[mi][ni][r];
        int code = bn * 128 + wc * 64 + ni * 16 + l15;
        if (v < best) { best = v; bi = code; }
      }
#pragma unroll
      for (int m = 1; m < 16; m <<= 1) {
        float ov = __shfl_xor(best, m, 64);
        int   oi = __shfl_xor(bi, m, 64);
        if (ov < best) { best = ov; bi = oi; }
      }
      if (l15 == 0) {
        int tloc = wr * 64 + mi * 16 + l4 * 4 + r;
        rv[wc][tloc] = best;
        ri[wc][tloc] = bi;
      }
    }
  }
  __syncthreads();
  if (tid < 128) {
    float v0 = rv[0][tid], v1 = rv[1][tid];
    int   i0 = ri[0][tid], i1 = ri[1][tid];
    float bv = v0; int bb = i0;
    if (v1 < bv) { bv = v1; bb = i1; }
    size_t g = (size_t)bn * NTOK + bm * 128 + tid;
    pval[g] = bv;
    pidx[g] = bb;
  }
}

__global__ void argmin_reduce(const float* __restrict__ pval, const int* __restrict__ pidx,
                              int* __restrict__ idx) {
  int t = blockIdx.x * 256 + threadIdx.x;   // 0..32767
  float best = 1e30f;
  int bi = 0;
  for (int c = 0; c < 32; c++) {
    float v = pval[(size_t)c * NTOK + t];
    if (v < best) { best = v; bi = pidx[(size_t)c * NTOK + t]; }
  }
  idx[t] = bi;
}

// ---------- gate GEMM (X @ W^T) + fused epilogue + deterministic loss -------
__global__ __launch_bounds__(256)
void gate_out(const u16* __restrict__ Xb, const u16* __restrict__ Wb,
              const float* __restrict__ X, const float* __restrict__ Cf,
              const float* __restrict__ gb, const int* __restrict__ idx,
              float* __restrict__ out, float* __restrict__ blockSum) {
  __shared__ u16 As[2][128 * 64];
  __shared__ u16 Bs[2][128 * 64];
  __shared__ float bsum[4];

  const int tid  = threadIdx.x;
  const int lane = tid & 63;
  const int wid  = tid >> 6;
  const int wr   = wid >> 1, wc = wid & 1;
  const int bm   = blockIdx.x;        // 0..255
  const int bn   = blockIdx.y;        // 0..3
  const int l15  = lane & 15, l4 = lane >> 4;
  const int srow = lane >> 3;
  const int scol = (lane & 7) * 8;

  const u16* Xrow = Xb + (size_t)(bm * 128) * DIM;
  const u16* Wrow = Wb + (size_t)(bn * 128) * DIM;

  auto stage = [&](int buf, int kk) {
#pragma unroll
    for (int i = 0; i < 4; i++) {
      int rA = (wid * 4 + i) * 8 + srow;
      gload_lds16(Xrow + (size_t)rA * DIM + kk + scol,
                  (void*)(As[buf] + (wid * 4 + i) * 512));
      gload_lds16(Wrow + (size_t)rA * DIM + kk + scol,
                  (void*)(Bs[buf] + (wid * 4 + i) * 512));
    }
  };

  f32x4 acc[4][4];
#pragma unroll
  for (int i = 0; i < 4; i++)
#pragma unroll
    for (int j = 0; j < 4; j++)
#pragma unroll
      for (int r = 0; r < 4; r++) acc[i][j][r] = 0.f;

  stage(0, 0);
  __syncthreads();
  int cur = 0;
  for (int t = 0; t < 8; ++t) {
    if (t < 7) stage(cur ^ 1, (t + 1) * 64);
#pragma unroll
    for (int ks = 0; ks < 2; ks++) {
      bf16x8 af[4], bfr[4];
#pragma unroll
      for (int mi = 0; mi < 4; mi++) {
        int row = wr * 64 + mi * 16 + l15;
        af[mi] = *reinterpret_cast<const bf16x8*>(As[cur] + row * 64 + ks * 32 + l4 * 8);
      }
#pragma unroll
      for (int ni = 0; ni < 4; ni++) {
        int row = wc * 64 + ni * 16 + l15;
        bfr[ni] = *reinterpret_cast<const bf16x8*>(Bs[cur] + row * 64 + ks * 32 + l4 * 8);
      }
#pragma unroll
      for (int mi = 0; mi < 4; mi++)
#pragma unroll
        for (int ni = 0; ni < 4; ni++)
          acc[mi][ni] = __builtin_amdgcn_mfma_f32_16x16x32_bf16(
              af[mi], bfr[ni], acc[mi][ni], 0, 0, 0);
    }
    __syncthreads();
    cur ^= 1;
  }

  // epilogue: gate = sigmoid(acc + b), out = x + c[idx]*gate, loss partial
  float lsum = 0.f;
#pragma unroll
  for (int mi = 0; mi < 4; mi++) {
#pragma unroll
    for (int r = 0; r < 4; r++) {
      int token = bm * 128 + wr * 64 + mi * 16 + l4 * 4 + r;
      int code = idx[token];
#pragma unroll
      for (int ni = 0; ni < 4; ni++) {
        int col = bn * 128 + wc * 64 + ni * 16 + l15;
        float logit = acc[mi][ni][r] + gb[col];
        float g = 1.0f / (1.0f + __expf(-logit));
        float q = Cf[(size_t)code * DIM + col];
        float xx = X[(size_t)token * DIM + col];
        out[(size_t)token * DIM + col] = xx + q * g;
        float d = q - xx;
        lsum += d * d;
      }
    }
  }
#pragma unroll
  for (int m = 1; m < 64; m <<= 1) lsum += __shfl_xor(lsum, m, 64);
  if (lane == 0) bsum[wid] = lsum;
  __syncthreads();
  if (tid == 0)
    blockSum[blockIdx.y * gridDim.x + blockIdx.x] = bsum[0] + bsum[1] + bsum[2] + bsum[3];
}

__global__ void finalize(const float* __restrict__ blockSum, float* __restrict__ out_loss) {
  int t = threadIdx.x;  // 256 threads, 1024 partials
  float s = 0.f;
#pragma unroll
  for (int i = 0; i < 4; i++) s += blockSum[t * 4 + i];
#pragma unroll
  for (int m = 1; m < 64; m <<= 1) s += __shfl_xor(s, m, 64);
  __shared__ float w4[4];
  if ((t & 63) == 0) w4[t >> 6] = s;
  __syncthreads();
  if (t == 0) {
    float tot = w4[0] + w4[1] + w4[2] + w4[3];
    out_loss[0] = 1.25f * tot / 16777216.0f;   // N*D = 32768*512
  }
}

extern "C" void kernel_launch(void* const* d_in, const int* in_sizes, int n_in,
                              void* d_out, int out_size, void* d_ws, size_t ws_size,
                              hipStream_t stream) {
  const float* X  = (const float*)d_in[0];   // [32768, 512]
  const float* CB = (const float*)d_in[1];   // [4096, 512]
  const float* GW = (const float*)d_in[2];   // [512, 512]
  const float* GB = (const float*)d_in[3];   // [512]
  float* out = (float*)d_out;                // [32768*512] output + [1] loss

  char* w = (char*)d_ws;
  size_t off = 0;
  auto alloc = [&](size_t bytes) -> void* {
    void* p = w + off;
    off = (off + bytes + 255) & ~(size_t)255;
    return p;
  };
  u16*   Xb    = (u16*)alloc((size_t)NTOK * DIM * 2);   // 33.5 MB
  u16*   Cb    = (u16*)alloc((size_t)KC * DIM * 2);     // 4.2 MB
  u16*   Wb    = (u16*)alloc((size_t)DIM * DIM * 2);    // 0.5 MB
  float* cnorm = (float*)alloc((size_t)KC * 4);
  float* pval  = (float*)alloc((size_t)32 * NTOK * 4);  // 4.2 MB
  int*   pidx  = (int*)alloc((size_t)32 * NTOK * 4);    // 4.2 MB
  int*   idx   = (int*)alloc((size_t)NTOK * 4);
  float* bsums = (float*)alloc((size_t)1024 * 4);

  cvt8<<<8192, 256, 0, stream>>>(X, Xb, NTOK * DIM / 8);
  cvt8<<<128, 256, 0, stream>>>(GW, Wb, DIM * DIM / 8);
  cvt_codebook<<<KC, 256, 0, stream>>>(CB, Cb, cnorm);
  argmin_gemm<<<dim3(256, 32), 256, 0, stream>>>(Xb, Cb, cnorm, pval, pidx);
  argmin_reduce<<<128, 256, 0, stream>>>(pval, pidx, idx);
  gate_out<<<dim3(256, 4), 256, 0, stream>>>(Xb, Wb, X, CB, GB, idx, out, bsums);
  finalize<<<1, 256, 0, stream>>>(bsums, out + (size_t)NTOK * DIM);
}

// Round 3
// 316.704 us; speedup vs baseline: 1.1018x; 1.1018x over previous
//
#include <hip/hip_runtime.h>
#include <hip/hip_bf16.h>

typedef unsigned short u16;
typedef __bf16 bf16x8 __attribute__((ext_vector_type(8)));
typedef float f32x4 __attribute__((ext_vector_type(4)));

#define NTOK 32768   // B*S = 8*4096
#define DIM  512
#define KC   4096

__device__ __forceinline__ u16 f2b(float f) {
  __hip_bfloat16 h = __float2bfloat16(f);
  return *reinterpret_cast<u16*>(&h);
}

__device__ __forceinline__ void gload_lds16(const void* g, void* l) {
  __builtin_amdgcn_global_load_lds(
      (__attribute__((address_space(1))) void*)g,
      (__attribute__((address_space(3))) void*)l,
      16, 0, 0);
}

// ---------------- prep: fp32 -> bf16 conversion (8 elems/thread) -------------
__global__ void cvt8(const float* __restrict__ in, u16* __restrict__ out, int n8) {
  int i = blockIdx.x * blockDim.x + threadIdx.x;
  if (i >= n8) return;
  const float4* p = reinterpret_cast<const float4*>(in) + 2 * (size_t)i;
  float4 a = p[0], b = p[1];
  uint4 v;
  v.x = (unsigned)f2b(a.x) | ((unsigned)f2b(a.y) << 16);
  v.y = (unsigned)f2b(a.z) | ((unsigned)f2b(a.w) << 16);
  v.z = (unsigned)f2b(b.x) | ((unsigned)f2b(b.y) << 16);
  v.w = (unsigned)f2b(b.z) | ((unsigned)f2b(b.w) << 16);
  reinterpret_cast<uint4*>(out)[i] = v;
}

// codebook -> bf16, plus per-row squared L2 norm (fp32, exact)
__global__ void cvt_codebook(const float* __restrict__ cb, u16* __restrict__ cbb,
                             float* __restrict__ cnorm) {
  int k = blockIdx.x;          // 0..4095
  int t = threadIdx.x;         // 0..255
  float c0 = cb[(size_t)k * DIM + t];
  float c1 = cb[(size_t)k * DIM + 256 + t];
  cbb[(size_t)k * DIM + t]       = f2b(c0);
  cbb[(size_t)k * DIM + 256 + t] = f2b(c1);
  float s = c0 * c0 + c1 * c1;
#pragma unroll
  for (int m = 1; m < 64; m <<= 1) s += __shfl_xor(s, m, 64);
  __shared__ float w4[4];
  if ((t & 63) == 0) w4[t >> 6] = s;
  __syncthreads();
  if (t == 0) cnorm[k] = w4[0] + w4[1] + w4[2] + w4[3];
}

// ---------------- argmin GEMM: scores = cnorm[k] - 2 * x.c ------------------
// 128x128 tile, BK=64 double-buffered, prefetch-before-compute, T2 XOR-swizzle
// (pre-swizzled global source + swizzled ds_read; LDS dest stays linear).
__global__ __launch_bounds__(256)
void argmin_gemm(const u16* __restrict__ Xb, const u16* __restrict__ Cb,
                 const float* __restrict__ cnorm,
                 float* __restrict__ pval, int* __restrict__ pidx) {
  __shared__ u16 As[2][128 * 64];
  __shared__ u16 Bs[2][128 * 64];
  __shared__ float rv[2][128];
  __shared__ int   ri[2][128];

  const int tid  = threadIdx.x;
  const int lane = tid & 63;
  const int wid  = tid >> 6;          // 0..3
  const int wr   = wid >> 1, wc = wid & 1;
  const int bm   = blockIdx.x;        // 0..255 token tiles
  const int bn   = blockIdx.y;        // 0..31  code tiles
  const int l15  = lane & 15, l4 = lane >> 4;
  // staging: lane l covers row (l>>3), 16B slot (l&7) of an 8-row chunk.
  // Source col is pre-swizzled so that the swizzled READ returns the right data.
  const int srow = lane >> 3;                              // 0..7
  const int scol = (((lane & 7) ^ (lane >> 3)) & 7) * 8;   // swizzled elem offset

  const u16* Xrow = Xb + (size_t)(bm * 128) * DIM;
  const u16* Crow = Cb + (size_t)(bn * 128) * DIM;

  auto stage = [&](int buf, int kk) {
#pragma unroll
    for (int i = 0; i < 4; i++) {
      int rA = (wid * 4 + i) * 8 + srow;   // 0..127
      gload_lds16(Xrow + (size_t)rA * DIM + kk + scol,
                  (void*)(As[buf] + (wid * 4 + i) * 512));
      gload_lds16(Crow + (size_t)rA * DIM + kk + scol,
                  (void*)(Bs[buf] + (wid * 4 + i) * 512));
    }
  };

  f32x4 acc[4][4];
#pragma unroll
  for (int i = 0; i < 4; i++)
#pragma unroll
    for (int j = 0; j < 4; j++)
#pragma unroll
      for (int r = 0; r < 4; r++) acc[i][j][r] = 0.f;

  stage(0, 0);
  __syncthreads();              // buf0 ready
  int cur = 0;
  for (int t = 0; t < 8; ++t) {
    if (t < 7) stage(cur ^ 1, (t + 1) * 64);   // prefetch next tile
#pragma unroll
    for (int ks = 0; ks < 2; ks++) {
      bf16x8 af[4], bfr[4];
#pragma unroll
      for (int mi = 0; mi < 4; mi++) {
        int row = wr * 64 + mi * 16 + l15;
        int col = (ks * 32 + l4 * 8) ^ ((row & 7) << 3);   // T2 swizzled read
        af[mi] = *reinterpret_cast<const bf16x8*>(As[cur] + row * 64 + col);
      }
#pragma unroll
      for (int ni = 0; ni < 4; ni++) {
        int row = wc * 64 + ni * 16 + l15;
        int col = (ks * 32 + l4 * 8) ^ ((row & 7) << 3);
        bfr[ni] = *reinterpret_cast<const bf16x8*>(Bs[cur] + row * 64 + col);
      }
#pragma unroll
      for (int mi = 0; mi < 4; mi++)
#pragma unroll
        for (int ni = 0; ni < 4; ni++)
          acc[mi][ni] = __builtin_amdgcn_mfma_f32_16x16x32_bf16(
              af[mi], bfr[ni], acc[mi][ni], 0, 0, 0);
    }
    __syncthreads();            // drains prefetch; next buf ready
    cur ^= 1;
  }

  // epilogue: per-token argmin over this block's 128 codes
  float cn[4];
#pragma unroll
  for (int ni = 0; ni < 4; ni++)
    cn[ni] = cnorm[bn * 128 + wc * 64 + ni * 16 + l15];

#pragma unroll
  for (int mi = 0; mi < 4; mi++) {
#pragma unroll
    for (int r = 0; r < 4; r++) {
      float best = 1e30f;
      int bi = 0;
#pragma unroll
      for (int ni = 0; ni < 4; ni++) {
        float v = cn[ni] - 2.0f * acc[mi][ni][r];
        int code = bn * 128 + wc * 64 + ni * 16 + l15;
        if (v < best) { best = v; bi = code; }
      }
#pragma unroll
      for (int m = 1; m < 16; m <<= 1) {
        float ov = __shfl_xor(best, m, 64);
        int   oi = __shfl_xor(bi, m, 64);
        if (ov < best) { best = ov; bi = oi; }
      }
      if (l15 == 0) {
        int tloc = wr * 64 + mi * 16 + l4 * 4 + r;
        rv[wc][tloc] = best;
        ri[wc][tloc] = bi;
      }
    }
  }
  __syncthreads();
  if (tid < 128) {
    float v0 = rv[0][tid], v1 = rv[1][tid];
    int   i0 = ri[0][tid], i1 = ri[1][tid];
    float bv = v0; int bb = i0;
    if (v1 < bv) { bv = v1; bb = i1; }
    size_t g = (size_t)bn * NTOK + bm * 128 + tid;
    pval[g] = bv;
    pidx[g] = bb;
  }
}

__global__ void argmin_reduce(const float* __restrict__ pval, const int* __restrict__ pidx,
                              int* __restrict__ idx) {
  int t = blockIdx.x * 256 + threadIdx.x;   // 0..32767
  float best = 1e30f;
  int bi = 0;
  for (int c = 0; c < 32; c++) {
    float v = pval[(size_t)c * NTOK + t];
    if (v < best) { best = v; bi = pidx[(size_t)c * NTOK + t]; }
  }
  idx[t] = bi;
}

// ---------- gate GEMM (X @ W^T) + fused epilogue + deterministic loss -------
__global__ __launch_bounds__(256)
void gate_out(const u16* __restrict__ Xb, const u16* __restrict__ Wb,
              const float* __restrict__ X, const float* __restrict__ Cf,
              const float* __restrict__ gb, const int* __restrict__ idx,
              float* __restrict__ out, float* __restrict__ blockSum) {
  __shared__ u16 As[2][128 * 64];
  __shared__ u16 Bs[2][128 * 64];
  __shared__ float bsum[4];

  const int tid  = threadIdx.x;
  const int lane = tid & 63;
  const int wid  = tid >> 6;
  const int wr   = wid >> 1, wc = wid & 1;
  const int bm   = blockIdx.x;        // 0..255
  const int bn   = blockIdx.y;        // 0..3
  const int l15  = lane & 15, l4 = lane >> 4;
  const int srow = lane >> 3;
  const int scol = (((lane & 7) ^ (lane >> 3)) & 7) * 8;

  const u16* Xrow = Xb + (size_t)(bm * 128) * DIM;
  const u16* Wrow = Wb + (size_t)(bn * 128) * DIM;

  auto stage = [&](int buf, int kk) {
#pragma unroll
    for (int i = 0; i < 4; i++) {
      int rA = (wid * 4 + i) * 8 + srow;
      gload_lds16(Xrow + (size_t)rA * DIM + kk + scol,
                  (void*)(As[buf] + (wid * 4 + i) * 512));
      gload_lds16(Wrow + (size_t)rA * DIM + kk + scol,
                  (void*)(Bs[buf] + (wid * 4 + i) * 512));
    }
  };

  f32x4 acc[4][4];
#pragma unroll
  for (int i = 0; i < 4; i++)
#pragma unroll
    for (int j = 0; j < 4; j++)
#pragma unroll
      for (int r = 0; r < 4; r++) acc[i][j][r] = 0.f;

  stage(0, 0);
  __syncthreads();
  int cur = 0;
  for (int t = 0; t < 8; ++t) {
    if (t < 7) stage(cur ^ 1, (t + 1) * 64);
#pragma unroll
    for (int ks = 0; ks < 2; ks++) {
      bf16x8 af[4], bfr[4];
#pragma unroll
      for (int mi = 0; mi < 4; mi++) {
        int row = wr * 64 + mi * 16 + l15;
        int col = (ks * 32 + l4 * 8) ^ ((row & 7) << 3);
        af[mi] = *reinterpret_cast<const bf16x8*>(As[cur] + row * 64 + col);
      }
#pragma unroll
      for (int ni = 0; ni < 4; ni++) {
        int row = wc * 64 + ni * 16 + l15;
        int col = (ks * 32 + l4 * 8) ^ ((row & 7) << 3);
        bfr[ni] = *reinterpret_cast<const bf16x8*>(Bs[cur] + row * 64 + col);
      }
#pragma unroll
      for (int mi = 0; mi < 4; mi++)
#pragma unroll
        for (int ni = 0; ni < 4; ni++)
          acc[mi][ni] = __builtin_amdgcn_mfma_f32_16x16x32_bf16(
              af[mi], bfr[ni], acc[mi][ni], 0, 0, 0);
    }
    __syncthreads();
    cur ^= 1;
  }

  // epilogue: gate = sigmoid(acc + b), out = x + c[idx]*gate, loss partial
  float lsum = 0.f;
#pragma unroll
  for (int mi = 0; mi < 4; mi++) {
#pragma unroll
    for (int r = 0; r < 4; r++) {
      int token = bm * 128 + wr * 64 + mi * 16 + l4 * 4 + r;
      int code = idx[token];
#pragma unroll
      for (int ni = 0; ni < 4; ni++) {
        int col = bn * 128 + wc * 64 + ni * 16 + l15;
        float logit = acc[mi][ni][r] + gb[col];
        float g = 1.0f / (1.0f + __expf(-logit));
        float q = Cf[(size_t)code * DIM + col];
        float xx = X[(size_t)token * DIM + col];
        out[(size_t)token * DIM + col] = xx + q * g;
        float d = q - xx;
        lsum += d * d;
      }
    }
  }
#pragma unroll
  for (int m = 1; m < 64; m <<= 1) lsum += __shfl_xor(lsum, m, 64);
  if (lane == 0) bsum[wid] = lsum;
  __syncthreads();
  if (tid == 0)
    blockSum[blockIdx.y * gridDim.x + blockIdx.x] = bsum[0] + bsum[1] + bsum[2] + bsum[3];
}

__global__ void finalize(const float* __restrict__ blockSum, float* __restrict__ out_loss) {
  int t = threadIdx.x;  // 256 threads, 1024 partials
  float s = 0.f;
#pragma unroll
  for (int i = 0; i < 4; i++) s += blockSum[t * 4 + i];
#pragma unroll
  for (int m = 1; m < 64; m <<= 1) s += __shfl_xor(s, m, 64);
  __shared__ float w4[4];
  if ((t & 63) == 0) w4[t >> 6] = s;
  __syncthreads();
  if (t == 0) {
    float tot = w4[0] + w4[1] + w4[2] + w4[3];
    out_loss[0] = 1.25f * tot / 16777216.0f;   // N*D = 32768*512
  }
}

extern "C" void kernel_launch(void* const* d_in, const int* in_sizes, int n_in,
                              void* d_out, int out_size, void* d_ws, size_t ws_size,
                              hipStream_t stream) {
  const float* X  = (const float*)d_in[0];   // [32768, 512]
  const float* CB = (const float*)d_in[1];   // [4096, 512]
  const float* GW = (const float*)d_in[2];   // [512, 512]
  const float* GB = (const float*)d_in[3];   // [512]
  float* out = (float*)d_out;                // [32768*512] output + [1] loss

  char* w = (char*)d_ws;
  size_t off = 0;
  auto alloc = [&](size_t bytes) -> void* {
    void* p = w + off;
    off = (off + bytes + 255) & ~(size_t)255;
    return p;
  };
  u16*   Xb    = (u16*)alloc((size_t)NTOK * DIM * 2);   // 33.5 MB
  u16*   Cb    = (u16*)alloc((size_t)KC * DIM * 2);     // 4.2 MB
  u16*   Wb    = (u16*)alloc((size_t)DIM * DIM * 2);    // 0.5 MB
  float* cnorm = (float*)alloc((size_t)KC * 4);
  float* pval  = (float*)alloc((size_t)32 * NTOK * 4);  // 4.2 MB
  int*   pidx  = (int*)alloc((size_t)32 * NTOK * 4);    // 4.2 MB
  int*   idx   = (int*)alloc((size_t)NTOK * 4);
  float* bsums = (float*)alloc((size_t)1024 * 4);

  cvt8<<<8192, 256, 0, stream>>>(X, Xb, NTOK * DIM / 8);
  cvt8<<<128, 256, 0, stream>>>(GW, Wb, DIM * DIM / 8);
  cvt_codebook<<<KC, 256, 0, stream>>>(CB, Cb, cnorm);
  argmin_gemm<<<dim3(256, 32), 256, 0, stream>>>(Xb, Cb, cnorm, pval, pidx);
  argmin_reduce<<<128, 256, 0, stream>>>(pval, pidx, idx);
  gate_out<<<dim3(256, 4), 256, 0, stream>>>(Xb, Wb, X, CB, GB, idx, out, bsums);
  finalize<<<1, 256, 0, stream>>>(bsums, out + (size_t)NTOK * DIM);
}

// Round 4
// 266.686 us; speedup vs baseline: 1.3085x; 1.1876x over previous
//
#include <hip/hip_runtime.h>
#include <hip/hip_bf16.h>

typedef unsigned short u16;
typedef __bf16 bf16x8 __attribute__((ext_vector_type(8)));
typedef float f32x4 __attribute__((ext_vector_type(4)));

#define NTOK 32768   // B*S = 8*4096
#define DIM  512
#define KC   4096

__device__ __forceinline__ u16 f2b(float f) {
  __hip_bfloat16 h = __float2bfloat16(f);
  return *reinterpret_cast<u16*>(&h);
}

__device__ __forceinline__ void gload_lds16(const void* g, void* l) {
  __builtin_amdgcn_global_load_lds(
      (__attribute__((address_space(1))) void*)g,
      (__attribute__((address_space(3))) void*)l,
      16, 0, 0);
}

// ---------------- prep: fp32 -> bf16 conversion (8 elems/thread) -------------
__global__ void cvt8(const float* __restrict__ in, u16* __restrict__ out, int n8) {
  int i = blockIdx.x * blockDim.x + threadIdx.x;
  if (i >= n8) return;
  const float4* p = reinterpret_cast<const float4*>(in) + 2 * (size_t)i;
  float4 a = p[0], b = p[1];
  uint4 v;
  v.x = (unsigned)f2b(a.x) | ((unsigned)f2b(a.y) << 16);
  v.y = (unsigned)f2b(a.z) | ((unsigned)f2b(a.w) << 16);
  v.z = (unsigned)f2b(b.x) | ((unsigned)f2b(b.y) << 16);
  v.w = (unsigned)f2b(b.z) | ((unsigned)f2b(b.w) << 16);
  reinterpret_cast<uint4*>(out)[i] = v;
}

// codebook -> bf16, plus per-row squared L2 norm (fp32, exact)
__global__ void cvt_codebook(const float* __restrict__ cb, u16* __restrict__ cbb,
                             float* __restrict__ cnorm) {
  int k = blockIdx.x;          // 0..4095
  int t = threadIdx.x;         // 0..255
  float c0 = cb[(size_t)k * DIM + t];
  float c1 = cb[(size_t)k * DIM + 256 + t];
  cbb[(size_t)k * DIM + t]       = f2b(c0);
  cbb[(size_t)k * DIM + 256 + t] = f2b(c1);
  float s = c0 * c0 + c1 * c1;
#pragma unroll
  for (int m = 1; m < 64; m <<= 1) s += __shfl_xor(s, m, 64);
  __shared__ float w4[4];
  if ((t & 63) == 0) w4[t >> 6] = s;
  __syncthreads();
  if (t == 0) cnorm[k] = w4[0] + w4[1] + w4[2] + w4[3];
}

// ---------------- argmin GEMM: scores = cnorm[k] - 2 * x.c ------------------
// 256x256 tile, BK=64, 8 waves (2M x 4N), counted-vmcnt 2-tile-deep pipeline
// (T3+T4), T2 XOR-swizzle (pre-swizzled source + swizzled read), T5 setprio.
__global__ __launch_bounds__(512, 2)
void argmin_gemm8(const u16* __restrict__ Xb, const u16* __restrict__ Cb,
                  const float* __restrict__ cnorm,
                  float* __restrict__ pval, int* __restrict__ pidx) {
  __shared__ u16 As[2][256 * 64];   // 64 KiB
  __shared__ u16 Bs[2][256 * 64];   // 64 KiB  (128 KiB total)

  const int tid  = threadIdx.x;
  const int lane = tid & 63;
  const int wid  = tid >> 6;          // 0..7
  const int wr   = wid >> 2;          // 0..1  (M half)
  const int wc   = wid & 3;           // 0..3  (N quarter)
  const int bm   = blockIdx.x;        // 0..127 token tiles
  const int bn   = blockIdx.y;        // 0..15  code tiles
  const int l15  = lane & 15, l4 = lane >> 4;
  const int srow = lane >> 3;                 // 0..7
  const int sslot = (lane & 7) ^ srow;        // pre-swizzled 16B slot (involution)

  const u16* Xrow = Xb + (size_t)(bm * 256) * DIM;
  const u16* Crow = Cb + (size_t)(bn * 256) * DIM;

  // stage one K-tile (A[256][64] + B[256][64]) -> buf; 8 gload_lds / thread
  auto stage = [&](int buf, int kt) {
    int kk = kt * 64;
#pragma unroll
    for (int j = 0; j < 4; j++) {
      int r = j * 64 + wid * 8 + srow;
      gload_lds16(Xrow + (size_t)r * DIM + kk + sslot * 8,
                  (void*)(As[buf] + (j * 64 + wid * 8) * 64));
      gload_lds16(Crow + (size_t)r * DIM + kk + sslot * 8,
                  (void*)(Bs[buf] + (j * 64 + wid * 8) * 64));
    }
  };

  f32x4 acc[8][4];
#pragma unroll
  for (int i = 0; i < 8; i++)
#pragma unroll
    for (int j = 0; j < 4; j++)
#pragma unroll
      for (int r = 0; r < 4; r++) acc[i][j][r] = 0.f;

  stage(0, 0);
  stage(1, 1);

  for (int t = 0; t < 8; ++t) {
    // wait: tile t landed; tile t+1's 8 loads stay in flight (counted vmcnt)
    if (t < 7) asm volatile("s_waitcnt vmcnt(8)" ::: "memory");
    else       asm volatile("s_waitcnt vmcnt(0)" ::: "memory");
    __builtin_amdgcn_s_barrier();          // all threads passed their vmcnt
    asm volatile("" ::: "memory");

    const u16* A  = As[t & 1];
    const u16* Bt = Bs[t & 1];
    // B fragments for this tile (reused across all 4 sub-phases)
    bf16x8 bfr[4][2];
#pragma unroll
    for (int ni = 0; ni < 4; ni++)
#pragma unroll
      for (int ks = 0; ks < 2; ks++) {
        int row = wc * 64 + ni * 16 + l15;
        int col = (ks * 32 + l4 * 8) ^ ((row & 7) << 3);
        bfr[ni][ks] = *reinterpret_cast<const bf16x8*>(Bt + row * 64 + col);
      }
#pragma unroll
    for (int q = 0; q < 4; q++) {          // 4 sub-phases, free-running
      bf16x8 af[2][2];
#pragma unroll
      for (int m = 0; m < 2; m++)
#pragma unroll
        for (int ks = 0; ks < 2; ks++) {
          int mi = q * 2 + m;
          int row = wr * 128 + mi * 16 + l15;
          int col = (ks * 32 + l4 * 8) ^ ((row & 7) << 3);
          af[m][ks] = *reinterpret_cast<const bf16x8*>(A + row * 64 + col);
        }
      __builtin_amdgcn_s_setprio(1);
#pragma unroll
      for (int m = 0; m < 2; m++)
#pragma unroll
        for (int ni = 0; ni < 4; ni++)
#pragma unroll
          for (int ks = 0; ks < 2; ks++)
            acc[q * 2 + m][ni] = __builtin_amdgcn_mfma_f32_16x16x32_bf16(
                af[m][ks], bfr[ni][ks], acc[q * 2 + m][ni], 0, 0, 0);
      __builtin_amdgcn_s_setprio(0);
    }

    asm volatile("" ::: "memory");
    __builtin_amdgcn_s_barrier();          // all waves done reading buf[t&1]
    asm volatile("" ::: "memory");
    if (t + 2 < 8) stage(t & 1, t + 2);    // refill the freed buffer
  }

  // ---------------- epilogue: per-token argmin over 256 codes ----------------
  float* rv = (float*)As;   // [4][256] — alias, safe after final barrier+drain
  int*   ri = (int*)Bs;
  __syncthreads();

#pragma unroll
  for (int mi = 0; mi < 8; mi++) {
#pragma unroll
    for (int r = 0; r < 4; r++) {
      float best = 1e30f;
      int bi = 0;
#pragma unroll
      for (int ni = 0; ni < 4; ni++) {
        int code = bn * 256 + wc * 64 + ni * 16 + l15;
        float v = cnorm[code] - 2.0f * acc[mi][ni][r];
        if (v < best) { best = v; bi = code; }
      }
#pragma unroll
      for (int m = 1; m < 16; m <<= 1) {
        float ov = __shfl_xor(best, m, 64);
        int   oi = __shfl_xor(bi, m, 64);
        if (ov < best) { best = ov; bi = oi; }
      }
      if (l15 == 0) {
        int tok = wr * 128 + mi * 16 + l4 * 4 + r;   // 0..255
        rv[wc * 256 + tok] = best;
        ri[wc * 256 + tok] = bi;
      }
    }
  }
  __syncthreads();
  if (tid < 256) {
    float bv = rv[tid];
    int   bb = ri[tid];
#pragma unroll
    for (int c = 1; c < 4; c++) {
      float v = rv[c * 256 + tid];
      if (v < bv) { bv = v; bb = ri[c * 256 + tid]; }
    }
    size_t g = (size_t)bn * NTOK + bm * 256 + tid;
    pval[g] = bv;
    pidx[g] = bb;
  }
}

__global__ void argmin_reduce(const float* __restrict__ pval, const int* __restrict__ pidx,
                              int* __restrict__ idx) {
  int t = blockIdx.x * 256 + threadIdx.x;   // 0..32767
  float best = 1e30f;
  int bi = 0;
  for (int c = 0; c < 16; c++) {
    float v = pval[(size_t)c * NTOK + t];
    if (v < best) { best = v; bi = pidx[(size_t)c * NTOK + t]; }
  }
  idx[t] = bi;
}

// ---------- gate GEMM (X @ W^T) + fused epilogue + deterministic loss -------
__global__ __launch_bounds__(256)
void gate_out(const u16* __restrict__ Xb, const u16* __restrict__ Wb,
              const float* __restrict__ X, const float* __restrict__ Cf,
              const float* __restrict__ gb, const int* __restrict__ idx,
              float* __restrict__ out, float* __restrict__ blockSum) {
  __shared__ u16 As[2][128 * 64];
  __shared__ u16 Bs[2][128 * 64];
  __shared__ float bsum[4];

  const int tid  = threadIdx.x;
  const int lane = tid & 63;
  const int wid  = tid >> 6;
  const int wr   = wid >> 1, wc = wid & 1;
  const int bm   = blockIdx.x;        // 0..255
  const int bn   = blockIdx.y;        // 0..3
  const int l15  = lane & 15, l4 = lane >> 4;
  const int srow = lane >> 3;
  const int scol = (((lane & 7) ^ (lane >> 3)) & 7) * 8;

  const u16* Xrow = Xb + (size_t)(bm * 128) * DIM;
  const u16* Wrow = Wb + (size_t)(bn * 128) * DIM;

  auto stage = [&](int buf, int kk) {
#pragma unroll
    for (int i = 0; i < 4; i++) {
      int rA = (wid * 4 + i) * 8 + srow;
      gload_lds16(Xrow + (size_t)rA * DIM + kk + scol,
                  (void*)(As[buf] + (wid * 4 + i) * 512));
      gload_lds16(Wrow + (size_t)rA * DIM + kk + scol,
                  (void*)(Bs[buf] + (wid * 4 + i) * 512));
    }
  };

  f32x4 acc[4][4];
#pragma unroll
  for (int i = 0; i < 4; i++)
#pragma unroll
    for (int j = 0; j < 4; j++)
#pragma unroll
      for (int r = 0; r < 4; r++) acc[i][j][r] = 0.f;

  stage(0, 0);
  __syncthreads();
  int cur = 0;
  for (int t = 0; t < 8; ++t) {
    if (t < 7) stage(cur ^ 1, (t + 1) * 64);
#pragma unroll
    for (int ks = 0; ks < 2; ks++) {
      bf16x8 af[4], bfr[4];
#pragma unroll
      for (int mi = 0; mi < 4; mi++) {
        int row = wr * 64 + mi * 16 + l15;
        int col = (ks * 32 + l4 * 8) ^ ((row & 7) << 3);
        af[mi] = *reinterpret_cast<const bf16x8*>(As[cur] + row * 64 + col);
      }
#pragma unroll
      for (int ni = 0; ni < 4; ni++) {
        int row = wc * 64 + ni * 16 + l15;
        int col = (ks * 32 + l4 * 8) ^ ((row & 7) << 3);
        bfr[ni] = *reinterpret_cast<const bf16x8*>(Bs[cur] + row * 64 + col);
      }
#pragma unroll
      for (int mi = 0; mi < 4; mi++)
#pragma unroll
        for (int ni = 0; ni < 4; ni++)
          acc[mi][ni] = __builtin_amdgcn_mfma_f32_16x16x32_bf16(
              af[mi], bfr[ni], acc[mi][ni], 0, 0, 0);
    }
    __syncthreads();
    cur ^= 1;
  }

  // epilogue: gate = sigmoid(acc + b), out = x + c[idx]*gate, loss partial
  float lsum = 0.f;
#pragma unroll
  for (int mi = 0; mi < 4; mi++) {
#pragma unroll
    for (int r = 0; r < 4; r++) {
      int token = bm * 128 + wr * 64 + mi * 16 + l4 * 4 + r;
      int code = idx[token];
#pragma unroll
      for (int ni = 0; ni < 4; ni++) {
        int col = bn * 128 + wc * 64 + ni * 16 + l15;
        float logit = acc[mi][ni][r] + gb[col];
        float g = 1.0f / (1.0f + __expf(-logit));
        float q = Cf[(size_t)code * DIM + col];
        float xx = X[(size_t)token * DIM + col];
        out[(size_t)token * DIM + col] = xx + q * g;
        float d = q - xx;
        lsum += d * d;
      }
    }
  }
#pragma unroll
  for (int m = 1; m < 64; m <<= 1) lsum += __shfl_xor(lsum, m, 64);
  if (lane == 0) bsum[wid] = lsum;
  __syncthreads();
  if (tid == 0)
    blockSum[blockIdx.y * gridDim.x + blockIdx.x] = bsum[0] + bsum[1] + bsum[2] + bsum[3];
}

__global__ void finalize(const float* __restrict__ blockSum, float* __restrict__ out_loss) {
  int t = threadIdx.x;  // 256 threads, 1024 partials
  float s = 0.f;
#pragma unroll
  for (int i = 0; i < 4; i++) s += blockSum[t * 4 + i];
#pragma unroll
  for (int m = 1; m < 64; m <<= 1) s += __shfl_xor(s, m, 64);
  __shared__ float w4[4];
  if ((t & 63) == 0) w4[t >> 6] = s;
  __syncthreads();
  if (t == 0) {
    float tot = w4[0] + w4[1] + w4[2] + w4[3];
    out_loss[0] = 1.25f * tot / 16777216.0f;   // N*D = 32768*512
  }
}

extern "C" void kernel_launch(void* const* d_in, const int* in_sizes, int n_in,
                              void* d_out, int out_size, void* d_ws, size_t ws_size,
                              hipStream_t stream) {
  const float* X  = (const float*)d_in[0];   // [32768, 512]
  const float* CB = (const float*)d_in[1];   // [4096, 512]
  const float* GW = (const float*)d_in[2];   // [512, 512]
  const float* GB = (const float*)d_in[3];   // [512]
  float* out = (float*)d_out;                // [32768*512] output + [1] loss

  char* w = (char*)d_ws;
  size_t off = 0;
  auto alloc = [&](size_t bytes) -> void* {
    void* p = w + off;
    off = (off + bytes + 255) & ~(size_t)255;
    return p;
  };
  u16*   Xb    = (u16*)alloc((size_t)NTOK * DIM * 2);   // 33.5 MB
  u16*   Cb    = (u16*)alloc((size_t)KC * DIM * 2);     // 4.2 MB
  u16*   Wb    = (u16*)alloc((size_t)DIM * DIM * 2);    // 0.5 MB
  float* cnorm = (float*)alloc((size_t)KC * 4);
  float* pval  = (float*)alloc((size_t)16 * NTOK * 4);  // 2.1 MB
  int*   pidx  = (int*)alloc((size_t)16 * NTOK * 4);    // 2.1 MB
  int*   idx   = (int*)alloc((size_t)NTOK * 4);
  float* bsums = (float*)alloc((size_t)1024 * 4);

  cvt8<<<8192, 256, 0, stream>>>(X, Xb, NTOK * DIM / 8);
  cvt8<<<128, 256, 0, stream>>>(GW, Wb, DIM * DIM / 8);
  cvt_codebook<<<KC, 256, 0, stream>>>(CB, Cb, cnorm);
  argmin_gemm8<<<dim3(128, 16), 512, 0, stream>>>(Xb, Cb, cnorm, pval, pidx);
  argmin_reduce<<<128, 256, 0, stream>>>(pval, pidx, idx);
  gate_out<<<dim3(256, 4), 256, 0, stream>>>(Xb, Wb, X, CB, GB, idx, out, bsums);
  finalize<<<1, 256, 0, stream>>>(bsums, out + (size_t)NTOK * DIM);
}